// Round 9
// baseline (309.363 us; speedup 1.0000x reference)
//
#include <hip/hip_runtime.h>
#include <stdint.h>

// ---------------------------------------------------------------------------
// EmbraceNet fused: out[b,e] = relu(x_f @ W_f + b_f)[b,e],  f = idx[b,e]
// idx = categorical(key=42): partitionable threefry, bits = y0^y1 of
// threefry2x32((0,42), (0, (e*4096+b)*4+f)); argmax over bits>>9, strict >.
// PASS since R4 (absmax 0.031).
//
// R9: (1) prep threefry rotates forced to v_alignbit via
// __builtin_rotateleft32 (R8 VALUBusy showed 5-inst rotates: 62us VALU vs
// 33us floor). (2) gemm back to 64x64 wave-tiles (256thr, 2x2 waves,
// 128x128 tile — minimal LDS bytes/FLOP; R7/R8's 64x32 split was 1.5x the
// b128 traffic) keeping R7's double-buffer + one barrier/kt. Swizzle
// dropped (R7==R8 conflict counter proved it's a fixed 4cyc/b128 cost).
// ---------------------------------------------------------------------------

typedef short short8 __attribute__((ext_vector_type(8)));
typedef float floatx4 __attribute__((ext_vector_type(4)));

#define B_DIM 4096
#define K_DIM 1024
#define E_DIM 2048

#if __has_builtin(__builtin_rotateleft32)
#define ROTL32(x, r) __builtin_rotateleft32((x), (r))
#else
#define ROTL32(x, r) __builtin_amdgcn_alignbit((x), (x), 32 - (r))
#endif

__device__ __forceinline__ uint16_t f2bf(float x) {
  uint32_t u = __float_as_uint(x);
  u += 0x7FFFu + ((u >> 16) & 1u);
  return (uint16_t)(u >> 16);
}

// JAX threefry2x32, key = (0, 42)
__device__ __forceinline__ void threefry(uint32_t x0, uint32_t x1,
                                         uint32_t& o0, uint32_t& o1) {
  const uint32_t ks0 = 0u;
  const uint32_t ks1 = 42u;
  const uint32_t ks2 = 0x1BD11BDAu ^ 42u;
  x0 += ks0; x1 += ks1;
#define TF_R(r) { x0 += x1; x1 = ROTL32(x1, r); x1 ^= x0; }
  TF_R(13) TF_R(15) TF_R(26) TF_R(6)
  x0 += ks1; x1 += ks2 + 1u;
  TF_R(17) TF_R(29) TF_R(16) TF_R(24)
  x0 += ks2; x1 += ks0 + 2u;
  TF_R(13) TF_R(15) TF_R(26) TF_R(6)
  x0 += ks0; x1 += ks1 + 3u;
  TF_R(17) TF_R(29) TF_R(16) TF_R(24)
  x0 += ks1; x1 += ks2 + 4u;
  TF_R(13) TF_R(15) TF_R(26) TF_R(6)
  x0 += ks2; x1 += ks0 + 5u;
#undef TF_R
  o0 = x0; o1 = x1;
}

// One dispatch, 26624 blocks, period-13 type pattern:
//   slot 0      -> idx     (2048 chunks)
//   slots 1..8  -> x conv  (16384 blocks: 4 planes x 4096)
//   slots 9..12 -> W conv  (8192 blocks: 4 planes x 2048)
__global__ __launch_bounds__(256) void prep_kernel(
    const float* __restrict__ x0, const float* __restrict__ x1,
    const float* __restrict__ x2, const float* __restrict__ x3,
    const float* __restrict__ W0, const float* __restrict__ W1,
    const float* __restrict__ W2, const float* __restrict__ W3,
    uint16_t* __restrict__ xb, uint16_t* __restrict__ Wt,
    uint32_t* __restrict__ idx2) {
  __shared__ float tile[32][33];
  const uint32_t g = blockIdx.x;
  const uint32_t chunk = g / 13u, slot = g % 13u;
  const int t = threadIdx.x;

  if (slot == 0) {
    // idx2[tid], tid = e*256 + b_hi: 2-bit sel for b = b_hi*16+j at bits 2j
    uint32_t tid = chunk * 256u + t;
    uint32_t base = tid << 6;
    uint32_t word = 0;
#pragma unroll 4
    for (int j = 0; j < 16; ++j) {
      uint32_t c = base + 4u * j;
      uint32_t best = 0, bi = 0;
#pragma unroll
      for (uint32_t f = 0; f < 4; ++f) {
        uint32_t y0, y1;
        threefry(0u, c + f, y0, y1);
        uint32_t m = (y0 ^ y1) >> 9;
        if (f == 0) best = m;
        else if (m > best) { best = m; bi = f; }
      }
      word |= bi << (2 * j);
    }
    idx2[tid] = word;
  } else if (slot <= 8) {
    uint32_t xi = chunk * 8u + (slot - 1);        // 0..16383
    int f = xi >> 12;
    const float* x = (f == 0) ? x0 : (f == 1) ? x1 : (f == 2) ? x2 : x3;
    size_t i = ((size_t)(xi & 4095) * 256 + t) * 4;
    float4 v = *(const float4*)(x + i);
    union { uint16_t h[4]; uint64_t q; } p;
    p.h[0] = f2bf(v.x); p.h[1] = f2bf(v.y);
    p.h[2] = f2bf(v.z); p.h[3] = f2bf(v.w);
    *(uint64_t*)(xb + (size_t)f * B_DIM * K_DIM + i) = p.q;
  } else {
    uint32_t wi = chunk * 4u + (slot - 9);        // 0..8191
    int f = wi >> 11;
    uint32_t ip = wi & 2047;
    const float* W = (f == 0) ? W0 : (f == 1) ? W1 : (f == 2) ? W2 : W3;
    int e0 = (ip & 63) * 32, k0 = (ip >> 6) * 32;
    int tx = t & 31, ty = t >> 5;
#pragma unroll
    for (int i = 0; i < 4; ++i)
      tile[ty + i * 8][tx] = W[(size_t)(k0 + ty + i * 8) * E_DIM + e0 + tx];
    __syncthreads();
    int el = t >> 3, kc = (t & 7) * 4;
    union { uint16_t h[4]; uint64_t q; } p;
#pragma unroll
    for (int i = 0; i < 4; ++i) p.h[i] = f2bf(tile[kc + i][el]);
    uint16_t* dst = Wt + (size_t)f * E_DIM * K_DIM;
    *(uint64_t*)(dst + (size_t)(e0 + el) * K_DIM + k0 + kc) = p.q;
  }
}

__device__ __forceinline__ void async16(const uint16_t* g, uint16_t* lds) {
  __builtin_amdgcn_global_load_lds(
      (const __attribute__((address_space(1))) void*)g,
      (__attribute__((address_space(3))) void*)lds, 16, 0, 0);
}

// 256 threads (4 waves, 2x2 of 64x64), 128x128 tile, f-loop inside,
// double-buffered LDS, one barrier per k-iter, dense single write.
__global__ __launch_bounds__(256, 2) void gemm_fused(
    const uint16_t* __restrict__ Ab, const uint16_t* __restrict__ Bbt,
    const uint32_t* __restrict__ idx2,
    const float* __restrict__ bias0, const float* __restrict__ bias1,
    const float* __restrict__ bias2, const float* __restrict__ bias3,
    float* __restrict__ out) {
  __shared__ uint16_t As[2][128 * 32];
  __shared__ uint16_t Bs[2][128 * 32];

  const int tid = threadIdx.x;
  const int w = tid >> 6;        // 0..3
  const int l = tid & 63;
  const int mBase = blockIdx.y * 128;
  const int nBase = blockIdx.x * 128;

  const int wm = (w >> 1) * 64, wn = (w & 1) * 64;
  const int sr = l >> 2, sc8 = l & 3;   // staging row-in-16, 8-col chunk
  const int fr = l & 15, fq = l >> 4;
  const int c0 = 2 * w, c1 = 2 * w + 1; // staged chunks for this wave

  const int b_hi0 = (mBase + wm) >> 4;
  uint32_t iw[4][4];
#pragma unroll
  for (int ni = 0; ni < 4; ++ni) {
    int col = nBase + wn + ni * 16 + fr;
#pragma unroll
    for (int mi = 0; mi < 4; ++mi)
      iw[ni][mi] = idx2[(size_t)col * (B_DIM / 16) + b_hi0 + mi];
  }

  floatx4 res[4][4] = {};

#pragma unroll 1
  for (int f = 0; f < 4; ++f) {
    const uint16_t* A = Ab  + (size_t)f * B_DIM * K_DIM + (size_t)mBase * K_DIM;
    const uint16_t* B = Bbt + (size_t)f * E_DIM * K_DIM + (size_t)nBase * K_DIM;
    const uint16_t* Ap0 = A + (size_t)(c0 * 16 + sr) * K_DIM + sc8 * 8;
    const uint16_t* Ap1 = A + (size_t)(c1 * 16 + sr) * K_DIM + sc8 * 8;
    const uint16_t* Bp0 = B + (size_t)(c0 * 16 + sr) * K_DIM + sc8 * 8;
    const uint16_t* Bp1 = B + (size_t)(c1 * 16 + sr) * K_DIM + sc8 * 8;

    floatx4 acc[4][4] = {};

    async16(Ap0, &As[0][c0 * 512]);
    async16(Ap1, &As[0][c1 * 512]);
    async16(Bp0, &Bs[0][c0 * 512]);
    async16(Bp1, &Bs[0][c1 * 512]);
    __syncthreads();

    int buf = 0;
#pragma unroll 1
    for (int kt = 0; kt < 32; ++kt) {
      int kn = (kt + 1) * 32;
      if (kt + 1 < 32) {  // next tile into other buffer, before compute
        async16(Ap0 + kn, &As[buf ^ 1][c0 * 512]);
        async16(Ap1 + kn, &As[buf ^ 1][c1 * 512]);
        async16(Bp0 + kn, &Bs[buf ^ 1][c0 * 512]);
        async16(Bp1 + kn, &Bs[buf ^ 1][c1 * 512]);
      }
      short8 a[4], b[4];
      #pragma unroll
      for (int mi = 0; mi < 4; ++mi)
        a[mi] = *(const short8*)&As[buf][(wm + mi * 16 + fr) * 32 + fq * 8];
      #pragma unroll
      for (int ni = 0; ni < 4; ++ni)
        b[ni] = *(const short8*)&Bs[buf][(wn + ni * 16 + fr) * 32 + fq * 8];
      #pragma unroll
      for (int mi = 0; mi < 4; ++mi)
        #pragma unroll
        for (int ni = 0; ni < 4; ++ni)
          acc[mi][ni] = __builtin_amdgcn_mfma_f32_16x16x32_bf16(
              a[mi], b[ni], acc[mi][ni], 0, 0, 0);
      __syncthreads();
      buf ^= 1;
    }

    const float* bias = (f == 0) ? bias0 : (f == 1) ? bias1
                      : (f == 2) ? bias2 : bias3;
    #pragma unroll
    for (int ni = 0; ni < 4; ++ni) {
      float bvf = bias[nBase + wn + ni * 16 + fr];
      #pragma unroll
      for (int mi = 0; mi < 4; ++mi) {
        uint32_t wd = iw[ni][mi];
        #pragma unroll
        for (int r = 0; r < 4; ++r) {
          uint32_t sel = (wd >> (2 * (fq * 4 + r))) & 3u;
          if (sel == (uint32_t)f) res[mi][ni][r] = acc[mi][ni][r] + bvf;
        }
      }
    }
  }

  // dense coalesced store with relu. C/D: col=lane&15, row=(lane>>4)*4+reg
#pragma unroll
  for (int ni = 0; ni < 4; ++ni) {
    int col = nBase + wn + ni * 16 + fr;
#pragma unroll
    for (int mi = 0; mi < 4; ++mi) {
      int row0 = mBase + wm + mi * 16 + fq * 4;
#pragma unroll
      for (int r = 0; r < 4; ++r) {
        float o = res[mi][ni][r];
        __builtin_nontemporal_store(o > 0.f ? o : 0.f,
                                    &out[(size_t)(row0 + r) * E_DIM + col]);
      }
    }
  }
}

extern "C" void kernel_launch(void* const* d_in, const int* in_sizes, int n_in,
                              void* d_out, int out_size, void* d_ws, size_t ws_size,
                              hipStream_t stream) {
  const float* x[4]; const float* W[4]; const float* bs[4];
  for (int f = 0; f < 4; ++f) {
    x[f]  = (const float*)d_in[3 * f + 0];
    W[f]  = (const float*)d_in[3 * f + 1];
    bs[f] = (const float*)d_in[3 * f + 2];
  }
  char* ws = (char*)d_ws;
  uint16_t* xb  = (uint16_t*)ws;                               // 32 MB
  uint16_t* Wt  = (uint16_t*)(ws + (size_t)32 * 1024 * 1024);  // 16 MB
  uint32_t* idx2 = (uint32_t*)(ws + (size_t)48 * 1024 * 1024); //  2 MB
  float* out = (float*)d_out;

  prep_kernel<<<dim3(26624), dim3(256), 0, stream>>>(
      x[0], x[1], x[2], x[3], W[0], W[1], W[2], W[3], xb, Wt, idx2);
  gemm_fused<<<dim3(E_DIM / 128, B_DIM / 128), dim3(256), 0, stream>>>(
      xb, Wt, idx2, bs[0], bs[1], bs[2], bs[3], out);
}

// Round 10
// 254.198 us; speedup vs baseline: 1.2170x; 1.2170x over previous
//
#include <hip/hip_runtime.h>
#include <stdint.h>

// ---------------------------------------------------------------------------
// EmbraceNet fused: out[b,e] = relu(x_f @ W_f + b_f)[b,e],  f = idx[b,e]
// idx = categorical(key=42): partitionable threefry, bits = y0^y1 of
// threefry2x32((0,42), (0, (e*4096+b)*4+f)); argmax over bits>>9, strict >.
// PASS since R4 (absmax 0.031).
//
// R10: (1) prep rebuilt with THREAD-level interleaving: each thread issues
// its x float4 loads + W tile loads, then crunches 16 threefry calls while
// they fly, then converts/stores (R9 showed block-level mixing starved
// converts to 950 GB/s via Little's law). 8192 uniform blocks; idx packed
// 4 outputs/byte — same dword layout the gemm already reads. (2) gemm BK=64:
// halves barrier count (128->64), doubles per-iter latency window; k-chunk
// XOR swizzle (by row&7) avoids the 128B-stride full bank collision while
// keeping global_load_lds contiguity (permute global source, not LDS dst).
// ---------------------------------------------------------------------------

typedef short short8 __attribute__((ext_vector_type(8)));
typedef float floatx4 __attribute__((ext_vector_type(4)));

#define B_DIM 4096
#define K_DIM 1024
#define E_DIM 2048

__device__ __forceinline__ uint32_t rotl32(uint32_t x, uint32_t r) {
  return __builtin_amdgcn_alignbit(x, x, 32u - r);
}

__device__ __forceinline__ uint16_t f2bf(float x) {
  uint32_t u = __float_as_uint(x);
  u += 0x7FFFu + ((u >> 16) & 1u);
  return (uint16_t)(u >> 16);
}

// JAX threefry2x32, key = (0, 42)
__device__ __forceinline__ void threefry(uint32_t x0, uint32_t x1,
                                         uint32_t& o0, uint32_t& o1) {
  const uint32_t ks0 = 0u;
  const uint32_t ks1 = 42u;
  const uint32_t ks2 = 0x1BD11BDAu ^ 42u;
  x0 += ks0; x1 += ks1;
#define TF_R(r) { x0 += x1; x1 = rotl32(x1, r); x1 ^= x0; }
  TF_R(13) TF_R(15) TF_R(26) TF_R(6)
  x0 += ks1; x1 += ks2 + 1u;
  TF_R(17) TF_R(29) TF_R(16) TF_R(24)
  x0 += ks2; x1 += ks0 + 2u;
  TF_R(13) TF_R(15) TF_R(26) TF_R(6)
  x0 += ks0; x1 += ks1 + 3u;
  TF_R(17) TF_R(29) TF_R(16) TF_R(24)
  x0 += ks1; x1 += ks2 + 4u;
  TF_R(13) TF_R(15) TF_R(26) TF_R(6)
  x0 += ks2; x1 += ks0 + 5u;
#undef TF_R
  o0 = x0; o1 = x1;
}

// 8192 blocks x 256 threads. Every thread: issue x loads (8 floats) + W
// loads (4 floats), crunch 4 idx outputs (16 threefry) while loads fly,
// then store x bf16 (16B), idx byte, and W transposed tile via LDS.
__global__ __launch_bounds__(256) void prep_kernel(
    const float* __restrict__ x0, const float* __restrict__ x1,
    const float* __restrict__ x2, const float* __restrict__ x3,
    const float* __restrict__ W0, const float* __restrict__ W1,
    const float* __restrict__ W2, const float* __restrict__ W3,
    uint16_t* __restrict__ xb, uint16_t* __restrict__ Wt,
    uint8_t* __restrict__ idx1) {
  __shared__ float tile[32][33];
  const uint32_t g = blockIdx.x;       // 0..8191
  const int t = threadIdx.x;
  const int f = g >> 11;               // plane 0..3
  const uint32_t ip = g & 2047u;       // tile/chunk within plane

  // ---- issue x loads: plane f, 8 consecutive floats per thread ----
  const float* x = (f == 0) ? x0 : (f == 1) ? x1 : (f == 2) ? x2 : x3;
  const size_t xoff = ((size_t)ip * 256 + t) * 8;
  float4 v0 = *(const float4*)(x + xoff);
  float4 v1 = *(const float4*)(x + xoff + 4);

  // ---- issue W loads: 32x32 tile ip of plane f ----
  const float* W = (f == 0) ? W0 : (f == 1) ? W1 : (f == 2) ? W2 : W3;
  const int e0 = (int)(ip & 63) * 32, k0 = (int)(ip >> 6) * 32;
  const int tx = t & 31, ty = t >> 5;
  float wv[4];
#pragma unroll
  for (int i = 0; i < 4; ++i)
    wv[i] = W[(size_t)(k0 + ty + i * 8) * E_DIM + e0 + tx];

  // ---- threefry crunch: outputs o0..o0+3, pack 2 bits each ----
  const uint32_t o0i = (g * 256u + t) * 4u;
  uint32_t byte = 0;
#pragma unroll
  for (uint32_t q = 0; q < 4; ++q) {
    uint32_t c = (o0i + q) << 2;
    uint32_t best = 0, bi = 0;
#pragma unroll
    for (uint32_t ff = 0; ff < 4; ++ff) {
      uint32_t y0, y1;
      threefry(0u, c + ff, y0, y1);
      uint32_t m = (y0 ^ y1) >> 9;
      if (ff == 0) best = m;
      else if (m > best) { best = m; bi = ff; }
    }
    byte |= bi << (2 * q);
  }
  idx1[g * 256u + t] = (uint8_t)byte;

  // ---- x store: 8 bf16 = 16B ----
  {
    union { uint16_t h[8]; uint64_t q[2]; } p;
    p.h[0] = f2bf(v0.x); p.h[1] = f2bf(v0.y);
    p.h[2] = f2bf(v0.z); p.h[3] = f2bf(v0.w);
    p.h[4] = f2bf(v1.x); p.h[5] = f2bf(v1.y);
    p.h[6] = f2bf(v1.z); p.h[7] = f2bf(v1.w);
    uint64_t* dst = (uint64_t*)(xb + (size_t)f * B_DIM * K_DIM + xoff);
    dst[0] = p.q[0]; dst[1] = p.q[1];
  }

  // ---- W transpose via LDS ----
#pragma unroll
  for (int i = 0; i < 4; ++i) tile[ty + i * 8][tx] = wv[i];
  __syncthreads();
  {
    const int el = t >> 3, kc = (t & 7) * 4;
    union { uint16_t h[4]; uint64_t q; } p;
#pragma unroll
    for (int i = 0; i < 4; ++i) p.h[i] = f2bf(tile[kc + i][el]);
    uint16_t* dst = Wt + (size_t)f * E_DIM * K_DIM;
    *(uint64_t*)(dst + (size_t)(e0 + el) * K_DIM + k0 + kc) = p.q;
  }
}

__device__ __forceinline__ void async16(const uint16_t* g, uint16_t* lds) {
  __builtin_amdgcn_global_load_lds(
      (const __attribute__((address_space(1))) void*)g,
      (__attribute__((address_space(3))) void*)lds, 16, 0, 0);
}

// 256 threads (4 waves, 2x2 of 64x64), 128x128 tile, BK=64, f-loop inside,
// double-buffered LDS (64KB), one barrier per 64-K iter (64 total).
// LDS[row][pos] holds global k-chunk pos^(row&7) (XOR swizzle, 8x16B chunks).
__global__ __launch_bounds__(256, 2) void gemm_fused(
    const uint16_t* __restrict__ Ab, const uint16_t* __restrict__ Bbt,
    const uint32_t* __restrict__ idx2,
    const float* __restrict__ bias0, const float* __restrict__ bias1,
    const float* __restrict__ bias2, const float* __restrict__ bias3,
    float* __restrict__ out) {
  __shared__ uint16_t As[2][128 * 64];
  __shared__ uint16_t Bs[2][128 * 64];

  const int tid = threadIdx.x;
  const int w = tid >> 6;        // 0..3
  const int l = tid & 63;
  const int mBase = blockIdx.y * 128;
  const int nBase = blockIdx.x * 128;

  const int wm = (w >> 1) * 64, wn = (w & 1) * 64;
  // staging: chunk c (8 rows of 64k); lane -> row sr, swizzled k-chunk
  const int sr = l >> 3;                 // 0..7 row within chunk
  const int skc = ((l & 7) ^ sr) * 8;    // global k-elem offset (swizzled)
  const int fr = l & 15, fq = l >> 4;

  const int b_hi0 = (mBase + wm) >> 4;
  uint32_t iw[4][4];
#pragma unroll
  for (int ni = 0; ni < 4; ++ni) {
    int col = nBase + wn + ni * 16 + fr;
#pragma unroll
    for (int mi = 0; mi < 4; ++mi)
      iw[ni][mi] = idx2[(size_t)col * (B_DIM / 16) + b_hi0 + mi];
  }

  floatx4 res[4][4] = {};

#pragma unroll 1
  for (int f = 0; f < 4; ++f) {
    const uint16_t* A = Ab  + (size_t)f * B_DIM * K_DIM + (size_t)mBase * K_DIM;
    const uint16_t* B = Bbt + (size_t)f * E_DIM * K_DIM + (size_t)nBase * K_DIM;
    // wave w stages chunks 4w..4w+3 of each matrix (chunk = 8 rows x 64 k)
    const uint16_t* Aw = A + (size_t)(32 * w + sr) * K_DIM + skc;
    const uint16_t* Bw = B + (size_t)(32 * w + sr) * K_DIM + skc;

    floatx4 acc[4][4] = {};

#pragma unroll
    for (int tt = 0; tt < 4; ++tt) {
      async16(Aw + (size_t)(8 * tt) * K_DIM, &As[0][(4 * w + tt) * 512]);
      async16(Bw + (size_t)(8 * tt) * K_DIM, &Bs[0][(4 * w + tt) * 512]);
    }
    __syncthreads();

    int buf = 0;
#pragma unroll 1
    for (int kt = 0; kt < 16; ++kt) {
      int kn = (kt + 1) * 64;
      if (kt + 1 < 16) {  // next 64-K tile into other buffer, before compute
#pragma unroll
        for (int tt = 0; tt < 4; ++tt) {
          async16(Aw + (size_t)(8 * tt) * K_DIM + kn, &As[buf ^ 1][(4 * w + tt) * 512]);
          async16(Bw + (size_t)(8 * tt) * K_DIM + kn, &Bs[buf ^ 1][(4 * w + tt) * 512]);
        }
      }
#pragma unroll
      for (int h = 0; h < 2; ++h) {
        short8 a[4], b[4];
        const int ch = h * 4 + fq;
#pragma unroll
        for (int mi = 0; mi < 4; ++mi) {
          int row = wm + mi * 16 + fr;
          a[mi] = *(const short8*)&As[buf][row * 64 + (ch ^ (fr & 7)) * 8];
        }
#pragma unroll
        for (int ni = 0; ni < 4; ++ni) {
          int row = wn + ni * 16 + fr;
          b[ni] = *(const short8*)&Bs[buf][row * 64 + (ch ^ (fr & 7)) * 8];
        }
#pragma unroll
        for (int mi = 0; mi < 4; ++mi)
#pragma unroll
          for (int ni = 0; ni < 4; ++ni)
            acc[mi][ni] = __builtin_amdgcn_mfma_f32_16x16x32_bf16(
                a[mi], b[ni], acc[mi][ni], 0, 0, 0);
      }
      __syncthreads();
      buf ^= 1;
    }

    const float* bias = (f == 0) ? bias0 : (f == 1) ? bias1
                      : (f == 2) ? bias2 : bias3;
#pragma unroll
    for (int ni = 0; ni < 4; ++ni) {
      float bvf = bias[nBase + wn + ni * 16 + fr];
#pragma unroll
      for (int mi = 0; mi < 4; ++mi) {
        uint32_t wd = iw[ni][mi];
#pragma unroll
        for (int r = 0; r < 4; ++r) {
          uint32_t sel = (wd >> (2 * (fq * 4 + r))) & 3u;
          if (sel == (uint32_t)f) res[mi][ni][r] = acc[mi][ni][r] + bvf;
        }
      }
    }
  }

  // dense coalesced store with relu. C/D: col=lane&15, row=(lane>>4)*4+reg
#pragma unroll
  for (int ni = 0; ni < 4; ++ni) {
    int col = nBase + wn + ni * 16 + fr;
#pragma unroll
    for (int mi = 0; mi < 4; ++mi) {
      int row0 = mBase + wm + mi * 16 + fq * 4;
#pragma unroll
      for (int r = 0; r < 4; ++r) {
        float o = res[mi][ni][r];
        __builtin_nontemporal_store(o > 0.f ? o : 0.f,
                                    &out[(size_t)(row0 + r) * E_DIM + col]);
      }
    }
  }
}

extern "C" void kernel_launch(void* const* d_in, const int* in_sizes, int n_in,
                              void* d_out, int out_size, void* d_ws, size_t ws_size,
                              hipStream_t stream) {
  const float* x[4]; const float* W[4]; const float* bs[4];
  for (int f = 0; f < 4; ++f) {
    x[f]  = (const float*)d_in[3 * f + 0];
    W[f]  = (const float*)d_in[3 * f + 1];
    bs[f] = (const float*)d_in[3 * f + 2];
  }
  char* ws = (char*)d_ws;
  uint16_t* xb  = (uint16_t*)ws;                               // 32 MB
  uint16_t* Wt  = (uint16_t*)(ws + (size_t)32 * 1024 * 1024);  // 16 MB
  uint8_t*  idx1 = (uint8_t*)(ws + (size_t)48 * 1024 * 1024);  //  2 MB
  float* out = (float*)d_out;

  prep_kernel<<<dim3(8192), dim3(256), 0, stream>>>(
      x[0], x[1], x[2], x[3], W[0], W[1], W[2], W[3], xb, Wt, idx1);
  gemm_fused<<<dim3(E_DIM / 128, B_DIM / 128), dim3(256), 0, stream>>>(
      xb, Wt, (const uint32_t*)idx1, bs[0], bs[1], bs[2], bs[3], out);
}